// Round 1
// baseline (145.640 us; speedup 1.0000x reference)
//
#include <hip/hip_runtime.h>
#include <math.h>

// Chamfer distance on MI355X (gfx950).
// B=8, N=M=8192, fp32. out = concat(dist1[B*N], dist2[B*M]).
//
// Strategy: pure-VALU pairwise scan. d = |q|^2 + |c|^2 - 2 q.c ; since |q|^2
// is constant per query, min_j d_j = |q|^2 + min_j (|c_j|^2 - 2 q.c_j), so the
// inner loop is 5 VALU ops/pair: mul, fma, fma, fma(-2,t,cw), min.
// Candidates staged in LDS as float4 (x,y,z,|c|^2); all lanes read the same
// address -> broadcast, no bank conflicts. Q=8 queries/thread in registers.
// Candidate axis split S ways across blocks; partial minima combined with
// atomicMin on float bits (valid: results clamped >= 0, uint order == float
// order for non-negative floats). d_out pre-set to 0x7f7f7f7f (large float).

#define BLOCK 256
#define Q 8
#define QB (BLOCK * Q)   // 2048 queries per block
#define CT 512           // candidates per block (LDS tile), 8 KB of float4

__global__ __launch_bounds__(BLOCK) void chamfer_kernel(
    const float* __restrict__ xyz1, const float* __restrict__ xyz2,
    float* __restrict__ out, int B, int N, int M)
{
    const int z   = blockIdx.z;      // [0, 2*B)
    const int dir = z / B;           // 0: queries=xyz1, cands=xyz2 ; 1: swapped
    const int b   = z % B;

    const float* qp; const float* cp; float* o; int Nq, Nc;
    if (dir == 0) {
        qp = xyz1 + (size_t)b * N * 3;
        cp = xyz2 + (size_t)b * M * 3;
        o  = out  + (size_t)b * N;
        Nq = N; Nc = M;
    } else {
        qp = xyz2 + (size_t)b * M * 3;
        cp = xyz1 + (size_t)b * N * 3;
        o  = out  + (size_t)B * N + (size_t)b * M;
        Nq = M; Nc = N;
    }

    // ---- stage candidate tile into LDS as (x, y, z, |c|^2) ----
    __shared__ float4 sc[CT];
    const int c0 = blockIdx.y * CT;
    for (int i = threadIdx.x; i < CT; i += BLOCK) {
        const int j = c0 + i;
        float x = 0.f, y = 0.f, zz = 0.f, sq = 3.0e38f;  // OOB -> "infinitely far"
        if (j < Nc) {
            x  = cp[3 * j + 0];
            y  = cp[3 * j + 1];
            zz = cp[3 * j + 2];
            sq = x * x + y * y + zz * zz;
        }
        sc[i] = make_float4(x, y, zz, sq);
    }
    __syncthreads();

    // ---- load Q queries per thread into registers ----
    const int n0 = blockIdx.x * QB + threadIdx.x;
    float qx[Q], qy[Q], qz[Q], mm[Q];
#pragma unroll
    for (int q = 0; q < Q; ++q) {
        const int n = n0 + q * BLOCK;
        float x = 0.f, y = 0.f, zz = 0.f;
        if (n < Nq) {
            x  = qp[3 * n + 0];
            y  = qp[3 * n + 1];
            zz = qp[3 * n + 2];
        }
        qx[q] = x; qy[q] = y; qz[q] = zz;
        mm[q] = 3.0e38f;
    }

    // ---- main scan: 5 VALU ops per (query, candidate) pair ----
#pragma unroll 4
    for (int j = 0; j < CT; ++j) {
        const float4 c = sc[j];   // wave-uniform address -> LDS broadcast
#pragma unroll
        for (int q = 0; q < Q; ++q) {
            float t = qx[q] * c.x;
            t = fmaf(qy[q], c.y, t);
            t = fmaf(qz[q], c.z, t);
            const float u = fmaf(t, -2.0f, c.w);   // |c|^2 - 2 q.c
            mm[q] = fminf(mm[q], u);
        }
    }

    // ---- epilogue: add |q|^2, clamp, merge partial min via uint atomicMin ----
#pragma unroll
    for (int q = 0; q < Q; ++q) {
        const int n = n0 + q * BLOCK;
        if (n < Nq) {
            float sq1 = qx[q] * qx[q];
            sq1 = fmaf(qy[q], qy[q], sq1);
            sq1 = fmaf(qz[q], qz[q], sq1);
            const float d = fmaxf(sq1 + mm[q], 0.0f);
            atomicMin((unsigned int*)(o + n), __float_as_uint(d));
        }
    }
}

extern "C" void kernel_launch(void* const* d_in, const int* in_sizes, int n_in,
                              void* d_out, int out_size, void* d_ws, size_t ws_size,
                              hipStream_t stream) {
    const float* xyz1 = (const float*)d_in[0];
    const float* xyz2 = (const float*)d_in[1];
    float* out = (float*)d_out;

    const int B = 8;                      // fixed by the reference problem
    const int N = in_sizes[0] / (B * 3);  // 8192
    const int M = in_sizes[1] / (B * 3);  // 8192

    // Initialize outputs to a huge positive float (0x7f7f7f7f) so uint
    // atomicMin of non-negative distances always wins. Re-done every call
    // (harness re-poisons d_out before each timed launch).
    hipMemsetAsync(d_out, 0x7f, (size_t)out_size * sizeof(float), stream);

    const int nmax = (N > M) ? N : M;
    dim3 grid((nmax + QB - 1) / QB,          // query chunks (4)
              (nmax + CT - 1) / CT,          // candidate splits (16)
              2 * B);                        // direction x batch (16)
    chamfer_kernel<<<grid, dim3(BLOCK), 0, stream>>>(xyz1, xyz2, out, B, N, M);
}

// Round 2
// 130.675 us; speedup vs baseline: 1.1145x; 1.1145x over previous
//
#include <hip/hip_runtime.h>
#include <math.h>

// Chamfer distance on MI355X (gfx950).
// B=8, N=M=8192, fp32. out = concat(dist1[B*N], dist2[B*M]).
//
// Round 2: 3.5 VALU ops/pair (was 5).
//  - LDS tile stores (-2x, -2y, -2z, |c|^2), so per candidate the partial
//    distance u = |c|^2 - 2 q.c is 3 chained FMAs seeded with c.w.
//  - Candidates processed in pairs; fminf(fminf(t0,t1),mm) is matched by the
//    AMDGPU backend to v_min3_f32, folding two mins into one instruction.
//  - grid.y 16->32 (CT 512->256): 2048 blocks = 8 blocks/CU = 8 waves/SIMD
//    for better issue-slot coverage; __launch_bounds__(256,8) caps VGPR<=64.
// Partial minima merged with uint atomicMin (valid for non-negative floats);
// d_out pre-set to 0x7f7f7f7f each call (harness zero/poisons it otherwise).

#define BLOCK 256
#define Q 8
#define QB (BLOCK * Q)   // 2048 queries per block
#define CT 256           // candidates per block tile (4 KB of float4 in LDS)

__global__ __launch_bounds__(BLOCK, 8) void chamfer_kernel(
    const float* __restrict__ xyz1, const float* __restrict__ xyz2,
    float* __restrict__ out, int B, int N, int M)
{
    const int z   = blockIdx.z;      // [0, 2*B)
    const int dir = z / B;           // 0: queries=xyz1, cands=xyz2 ; 1: swapped
    const int b   = z % B;

    const float* qp; const float* cp; float* o; int Nq, Nc;
    if (dir == 0) {
        qp = xyz1 + (size_t)b * N * 3;
        cp = xyz2 + (size_t)b * M * 3;
        o  = out  + (size_t)b * N;
        Nq = N; Nc = M;
    } else {
        qp = xyz2 + (size_t)b * M * 3;
        cp = xyz1 + (size_t)b * N * 3;
        o  = out  + (size_t)B * N + (size_t)b * M;
        Nq = M; Nc = N;
    }

    // ---- stage candidate tile into LDS as (-2x, -2y, -2z, |c|^2) ----
    __shared__ float4 sc[CT];
    const int c0 = blockIdx.y * CT;
    for (int i = threadIdx.x; i < CT; i += BLOCK) {
        const int j = c0 + i;
        float x = 0.f, y = 0.f, zz = 0.f, sq = 3.0e38f;  // OOB -> "infinitely far"
        if (j < Nc) {
            x  = cp[3 * j + 0];
            y  = cp[3 * j + 1];
            zz = cp[3 * j + 2];
            sq = x * x + y * y + zz * zz;
        }
        sc[i] = make_float4(-2.f * x, -2.f * y, -2.f * zz, sq);
    }
    __syncthreads();

    // ---- load Q queries per thread into registers ----
    const int n0 = blockIdx.x * QB + threadIdx.x;
    float qx[Q], qy[Q], qz[Q], mm[Q];
#pragma unroll
    for (int q = 0; q < Q; ++q) {
        const int n = n0 + q * BLOCK;
        float x = 0.f, y = 0.f, zz = 0.f;
        if (n < Nq) {
            x  = qp[3 * n + 0];
            y  = qp[3 * n + 1];
            zz = qp[3 * n + 2];
        }
        qx[q] = x; qy[q] = y; qz[q] = zz;
        mm[q] = 3.0e38f;
    }

    // ---- main scan: candidate pairs, 7 VALU ops per (query, 2 candidates) ----
#pragma unroll 2
    for (int j = 0; j < CT; j += 2) {
        const float4 ca = sc[j];       // wave-uniform address -> LDS broadcast
        const float4 cb = sc[j + 1];
#pragma unroll
        for (int q = 0; q < Q; ++q) {
            float t0 = fmaf(qx[q], ca.x, ca.w);
            t0 = fmaf(qy[q], ca.y, t0);
            t0 = fmaf(qz[q], ca.z, t0);
            float t1 = fmaf(qx[q], cb.x, cb.w);
            t1 = fmaf(qy[q], cb.y, t1);
            t1 = fmaf(qz[q], cb.z, t1);
            mm[q] = fminf(fminf(t0, t1), mm[q]);   // -> v_min3_f32
        }
    }

    // ---- epilogue: add |q|^2, clamp, merge partial min via uint atomicMin ----
#pragma unroll
    for (int q = 0; q < Q; ++q) {
        const int n = n0 + q * BLOCK;
        if (n < Nq) {
            float sq1 = qx[q] * qx[q];
            sq1 = fmaf(qy[q], qy[q], sq1);
            sq1 = fmaf(qz[q], qz[q], sq1);
            const float d = fmaxf(sq1 + mm[q], 0.0f);
            atomicMin((unsigned int*)(o + n), __float_as_uint(d));
        }
    }
}

extern "C" void kernel_launch(void* const* d_in, const int* in_sizes, int n_in,
                              void* d_out, int out_size, void* d_ws, size_t ws_size,
                              hipStream_t stream) {
    const float* xyz1 = (const float*)d_in[0];
    const float* xyz2 = (const float*)d_in[1];
    float* out = (float*)d_out;

    const int B = 8;                      // fixed by the reference problem
    const int N = in_sizes[0] / (B * 3);  // 8192
    const int M = in_sizes[1] / (B * 3);  // 8192

    // Initialize outputs to a huge positive float (0x7f7f7f7f) so uint
    // atomicMin of non-negative distances always wins.
    hipMemsetAsync(d_out, 0x7f, (size_t)out_size * sizeof(float), stream);

    const int nmax = (N > M) ? N : M;
    dim3 grid((nmax + QB - 1) / QB,          // query chunks (4)
              (nmax + CT - 1) / CT,          // candidate splits (32)
              2 * B);                        // direction x batch (16)
    chamfer_kernel<<<grid, dim3(BLOCK), 0, stream>>>(xyz1, xyz2, out, B, N, M);
}